// Round 7
// baseline (327.572 us; speedup 1.0000x reference)
//
#include <hip/hip_runtime.h>
#include <cstdint>
#include <cstddef>

// GCN link prediction forward:
//   Y1 = x@W1; H = relu(adj@Y1 + b1); Y2 = H@W2; Z = adj@Y2 + b2; out = sigmoid(Z@Z^T)
// GEMMs: bf16 MFMA (f32 accum), BT form: C[m][n] = sum_k A[m][k]*BT[n][k].
// adj is consumed TWICE in f32 (gemm2, gemm4) by gemm_adj with a T3/T4
// counted-vmcnt pipeline: A staged 3-deep in LDS via global_load_lds
// (source-pre-swizzled chunks), B (L2-hot) 2-deep in registers, raw s_barrier
// with s_waitcnt vmcnt(2) -- A-DMA is never drained to 0 inside the K-loop.
// d_out carve (dead until gemm5 overwrites all 256 MiB at the end):
//   [0,64M)    Hp: f32 partials of gemm2   [8][8192][256]
//   [64M,80M)  Zp: f32 partials of gemm4   [8][8192][64]

typedef unsigned short u16;
typedef __attribute__((ext_vector_type(8))) short short8;   // 8 bf16 (MFMA A/B frag)
typedef __attribute__((ext_vector_type(4))) float f32x4;    // MFMA C/D frag
typedef __attribute__((ext_vector_type(8))) unsigned short ushort8;
typedef __attribute__((ext_vector_type(4))) unsigned short u16x4;

__device__ __forceinline__ u16 f2bf(float v) {
    union { float f; unsigned int u; } c; c.f = v;
    unsigned int r = c.u + 0x7FFFu + ((c.u >> 16) & 1u);   // RNE
    return (u16)(r >> 16);
}

// packed f32 pair -> 2x bf16 (RNE), T12 recipe (no builtin on gfx950)
__device__ __forceinline__ unsigned cvt_pk(float lo, float hi) {
    unsigned r;
    asm("v_cvt_pk_bf16_f32 %0, %1, %2" : "=v"(r) : "v"(lo), "v"(hi));
    return r;
}
__device__ __forceinline__ short8 pack8(f32x4 lo, f32x4 hi) {
    union { short8 s; unsigned u[4]; } x;
    x.u[0] = cvt_pk(lo[0], lo[1]); x.u[1] = cvt_pk(lo[2], lo[3]);
    x.u[2] = cvt_pk(hi[0], hi[1]); x.u[3] = cvt_pk(hi[2], hi[3]);
    return x.s;
}

__device__ __forceinline__ void gload16(const void* g, void* l) {
    auto gp = (const __attribute__((address_space(1))) void*)(
        reinterpret_cast<uintptr_t>(g));
    auto lp = (__attribute__((address_space(3))) void*)(
        reinterpret_cast<uintptr_t>(l));
    __builtin_amdgcn_global_load_lds(gp, lp, 16, 0, 0);
}

// ---------------------------------------------------------------------------
// gemm_adj: Cp[z][m][n] = sum_{k in z-slab} adj_f32[m][k] * B_bf16[n][k]
// BM=128, BK=32, 512 threads (8 waves = NWR x NWC), split-K via blockIdx.z.
// Counted-vmcnt schedule per K-step kt:
//   loadB(kt+1) -> regs (NI instrs) ; stageA(kt+2) -> LDS buf[(kt+2)%3] (2 instrs)
//   compute(kt) from buf[kt%3] (ds_read + cvt_pk + MFMA)
//   s_waitcnt vmcnt(2)   // retires stageA(kt+1) + loadB(kt+1); stageA(kt+2) stays in flight
//   s_barrier (raw)      // no compiler vmcnt(0) drain
// A source chunks pre-swizzled lc = pc^(row&7): linear DMA dest + swizzled
// frag read => 16-way bank conflict -> 2-way (free).
// ---------------------------------------------------------------------------
template <int BN, int NWR, int NWC>
__launch_bounds__(512, 4)
__global__ void gemm_adj(const float* __restrict__ A32,
                         const u16* __restrict__ B,
                         float* __restrict__ Cp,
                         int lda, int ldb, int kLen) {
    constexpr int BM = 128, BK = 32;
    constexpr int WM = BM / NWR, WN = BN / NWC;
    constexpr int MI = WM / 16, NI = WN / 16;

    __shared__ float Al[3][BM * BK];          // 3 x 16 KB

    const int tid = threadIdx.x;
    const int l = tid & 63, w = tid >> 6;
    const int wr = w / NWC, wc = w % NWC;
    const int lr = l & 15, lk = l >> 4;
    const int m0 = blockIdx.y * BM;
    const int kbase = blockIdx.z * kLen;

    const float* Abase = A32 + (size_t)m0 * lda + kbase;
    const u16*   Bbase = B + kbase;

    auto stageA = [&](int buf, int kt) {
        const float* a = Abase + kt * BK;
#pragma unroll
        for (int i = 0; i < 2; i++) {
            int p = tid + i * 512;            // phys chunk 0..1023
            int row = p >> 3, pc = p & 7;
            int lc = pc ^ (row & 7);          // pre-swizzled source chunk
            gload16(a + (size_t)row * lda + lc * 4, (char*)&Al[buf][0] + p * 16);
        }
    };
    auto loadB = [&](short8* dst, int kt) {
#pragma unroll
        for (int ni = 0; ni < NI; ++ni)
            dst[ni] = *(const short8*)(Bbase +
                (size_t)(wc * WN + ni * 16 + lr) * ldb + kt * BK + lk * 8);
    };

    f32x4 acc[MI][NI] = {};
    short8 bcur[NI], bnxt[NI];
    const int ksteps = kLen / BK;

    // prologue: FIFO = stageA(0)[2], loadB(0)[NI], stageA(1)[2]
    stageA(0, 0);
    loadB(bcur, 0);
    stageA(1, 1);
    asm volatile("s_waitcnt vmcnt(2)" ::: "memory");   // stage0+B0 done; stage1 in flight
    __builtin_amdgcn_s_barrier();

    for (int kt = 0; kt < ksteps; ++kt) {
        if (kt + 1 < ksteps) loadB(bnxt, kt + 1);
        if (kt + 2 < ksteps) stageA((kt + 2) % 3, kt + 2);

        const float* Ab = &Al[kt % 3][0];
#pragma unroll
        for (int mi = 0; mi < MI; ++mi) {
            const int row = wr * WM + mi * 16 + lr;
            const int s = row & 7;
            const int c0 = lk * 2;
            const float* rb = Ab + row * BK;
            f32x4 lo = *(const f32x4*)(rb + ((c0 ^ s) << 2));
            f32x4 hi = *(const f32x4*)(rb + (((c0 + 1) ^ s) << 2));
            short8 af = pack8(lo, hi);
#pragma unroll
            for (int ni = 0; ni < NI; ++ni)
                acc[mi][ni] = __builtin_amdgcn_mfma_f32_16x16x32_bf16(
                    af, bcur[ni], acc[mi][ni], 0, 0, 0);
        }

        if (kt + 1 < ksteps) {
            if (kt + 2 < ksteps)
                asm volatile("s_waitcnt vmcnt(2)" ::: "memory");  // keep stage(kt+2) flying
            else
                asm volatile("s_waitcnt vmcnt(0)" ::: "memory");  // tail: drain all
            __builtin_amdgcn_s_barrier();
#pragma unroll
            for (int ni = 0; ni < NI; ++ni) bcur[ni] = bnxt[ni];
        }
    }

    // epilogue: f32 partial slab z.  C/D frag: col=lane&15, row=(lane>>4)*4+r
    float* C = Cp + (size_t)blockIdx.z * ((size_t)8192 * BN);
#pragma unroll
    for (int mi = 0; mi < MI; ++mi)
#pragma unroll
        for (int ni = 0; ni < NI; ++ni) {
            const int row = m0 + wr * WM + mi * 16 + lk * 4;
            const int col = wc * WN + ni * 16 + lr;
#pragma unroll
            for (int r = 0; r < 4; r++)
                C[(size_t)(row + r) * BN + col] = acc[mi][ni][r];
        }
}

// ---------------------------------------------------------------------------
// Templated bf16 BT-GEMM (both operands bf16). BK=64, MFMA 16x16x32.
// EPI: 0 = store bf16 ; 4 = sigmoid f32
// ---------------------------------------------------------------------------
template <int BM, int BN, int WM, int WN, int EPI>
__launch_bounds__((BM / WM) * (BN / WN) * 64, 2)
__global__ void gemm_bt(const u16* __restrict__ A, int lda,
                        const u16* __restrict__ B, int ldb,
                        void* __restrict__ C, int ldc,
                        const float* __restrict__ bias,
                        int M, int N, int kLen) {
    constexpr int BK = 64;
    constexpr int NWCOL = BN / WN;
    constexpr int NWAVES = (BM / WM) * (BN / WN);
    constexpr int THREADS = NWAVES * 64;
    constexpr int MI = WM / 16, NI = WN / 16;
    constexpr int A_LOADS = (BM * BK * 2) / (THREADS * 16);
    constexpr int B_LOADS = (BN * BK * 2) / (THREADS * 16);

    __shared__ u16 Al[2][BM * BK];
    __shared__ u16 Bl[2][BN * BK];

    const int tid = threadIdx.x;
    const int m0 = blockIdx.y * BM;
    const int n0 = blockIdx.x * BN;
    const int kbase = blockIdx.z * kLen;

    const int l = tid & 63;
    const int w = tid >> 6;
    const int wr = w / NWCOL, wc = w % NWCOL;
    const int lr = l & 15, lk = l >> 4;

    const size_t ldab = (size_t)lda * 2, ldbb = (size_t)ldb * 2;
    const char* Abase = (const char*)(A + (size_t)m0 * lda + kbase);
    const char* Bbase = (const char*)(B + (size_t)n0 * ldb + kbase);

    auto stage = [&](int buf, int kt) {
        const char* a = Abase + (size_t)kt * (BK * 2);
        const char* b = Bbase + (size_t)kt * (BK * 2);
#pragma unroll
        for (int i = 0; i < A_LOADS; i++) {
            int off = (tid + i * THREADS) * 16;
            gload16(a + (size_t)(off >> 7) * ldab + (off & 127),
                    (char*)&Al[buf][0] + off);
        }
#pragma unroll
        for (int i = 0; i < B_LOADS; i++) {
            int off = (tid + i * THREADS) * 16;
            gload16(b + (size_t)(off >> 7) * ldbb + (off & 127),
                    (char*)&Bl[buf][0] + off);
        }
    };

    f32x4 acc[MI][NI] = {};

    const int ksteps = kLen / BK;
    stage(0, 0);
    for (int kt = 0; kt < ksteps; ++kt) {
        const int cur = kt & 1;
        __syncthreads();
        if (kt + 1 < ksteps) stage(cur ^ 1, kt + 1);
#pragma unroll
        for (int ks = 0; ks < 2; ++ks) {
            short8 af[MI];
            short8 bf[NI];
#pragma unroll
            for (int mi = 0; mi < MI; ++mi)
                af[mi] = *(const short8*)&Al[cur][(wr * WM + mi * 16 + lr) * BK + ks * 32 + lk * 8];
#pragma unroll
            for (int ni = 0; ni < NI; ++ni)
                bf[ni] = *(const short8*)&Bl[cur][(wc * WN + ni * 16 + lr) * BK + ks * 32 + lk * 8];
#pragma unroll
            for (int mi = 0; mi < MI; ++mi)
#pragma unroll
                for (int ni = 0; ni < NI; ++ni)
                    acc[mi][ni] = __builtin_amdgcn_mfma_f32_16x16x32_bf16(
                        af[mi], bf[ni], acc[mi][ni], 0, 0, 0);
        }
    }

    // epilogue: C/D frag mapping col=lane&15, row=(lane>>4)*4+r  [m89-verified]
#pragma unroll
    for (int mi = 0; mi < MI; ++mi) {
#pragma unroll
        for (int ni = 0; ni < NI; ++ni) {
            const int row = m0 + wr * WM + mi * 16 + lk * 4;
            const int col = n0 + wc * WN + ni * 16 + lr;
            f32x4 v = acc[mi][ni];
            if constexpr (EPI == 0) {
                u16* Cp = (u16*)C;
#pragma unroll
                for (int r = 0; r < 4; r++)
                    Cp[(size_t)(row + r) * ldc + col] = f2bf(v[r]);
            } else if constexpr (EPI == 4) {
                float* Cp = (float*)C;
#pragma unroll
                for (int r = 0; r < 4; r++) {
                    float s = 1.0f / (1.0f + __expf(-v[r]));
                    Cp[(size_t)(row + r) * ldc + col] = s;
                }
            }
        }
    }
}

// ---------------------------------------------------------------------------
__global__ void cvt8(const float* __restrict__ in, u16* __restrict__ out, int n8) {
    int stride = gridDim.x * blockDim.x;
    for (int i = blockIdx.x * blockDim.x + threadIdx.x; i < n8; i += stride) {
        f32x4 a = ((const f32x4*)in)[2 * (size_t)i];
        f32x4 b = ((const f32x4*)in)[2 * (size_t)i + 1];
        ushort8 o;
        o[0] = f2bf(a[0]); o[1] = f2bf(a[1]); o[2] = f2bf(a[2]); o[3] = f2bf(a[3]);
        o[4] = f2bf(b[0]); o[5] = f2bf(b[1]); o[6] = f2bf(b[2]); o[7] = f2bf(b[3]);
        ((ushort8*)out)[i] = o;
    }
}

__global__ void trcvt(const float* __restrict__ in, u16* __restrict__ out, int R, int C) {
    int i = blockIdx.x * blockDim.x + threadIdx.x;
    if (i < R * C) {
        int r = i / C, c = i - r * C;
        out[(size_t)c * R + r] = f2bf(in[i]);
    }
}

// split-K reduce: out[i] = bf16( [relu]( sum_z p[z][i] + bias[i & colmask] ) )
template <int PARTS, bool RELU>
__global__ void reduce_add(const float* __restrict__ p, const float* __restrict__ bias,
                           u16* __restrict__ out, int n, int colmask) {
    int i = (blockIdx.x * blockDim.x + threadIdx.x) * 4;
    if (i >= n) return;
    f32x4 acc = *(const f32x4*)(p + i);
#pragma unroll
    for (int z = 1; z < PARTS; z++) {
        f32x4 q = *(const f32x4*)(p + (size_t)z * n + i);
        acc[0] += q[0]; acc[1] += q[1]; acc[2] += q[2]; acc[3] += q[3];
    }
    u16x4 o;
#pragma unroll
    for (int j = 0; j < 4; j++) {
        float v = acc[j] + bias[(i + j) & colmask];
        if constexpr (RELU) v = v > 0.f ? v : 0.f;
        o[j] = f2bf(v);
    }
    *(u16x4*)(out + i) = o;
}

// ---------------------------------------------------------------------------
extern "C" void kernel_launch(void* const* d_in, const int* in_sizes, int n_in,
                              void* d_out, int out_size, void* d_ws, size_t ws_size,
                              hipStream_t stream) {
    constexpr int N = 8192, F = 512, H = 256, CL = 64;

    const float* x   = (const float*)d_in[0];
    const float* adj = (const float*)d_in[1];
    const float* W1  = (const float*)d_in[2];
    const float* b1  = (const float*)d_in[3];
    const float* W2  = (const float*)d_in[4];
    const float* b2  = (const float*)d_in[5];
    float* out = (float*)d_out;

    // d_out carve (all dead before gemm5 overwrites the full 256 MiB)
    float* Hp = (float*)d_out;                                       // 64 MiB: [8][8192][256]
    float* Zp = (float*)((char*)d_out + (size_t)64 * 1024 * 1024);   // 16 MiB: [8][8192][64]

    // workspace carve-up (~18.3 MB total)
    u16* xb   = (u16*)d_ws;                       // [8192][512]
    u16* W1tb = xb   + (size_t)N * F;             // [256][512]
    u16* Y1tb = W1tb + (size_t)H * F;             // [256][8192]
    u16* Hb   = Y1tb + (size_t)H * N;             // [8192][256]
    u16* W2tb = Hb   + (size_t)N * H;             // [64][256]
    u16* Y2tb = W2tb + (size_t)CL * H;            // [64][8192]
    u16* Zb   = Y2tb + (size_t)CL * N;            // [8192][64]

    // small conversions
    cvt8<<<256, 256, 0, stream>>>(x, xb, N * F / 8);
    trcvt<<<(F * H + 255) / 256, 256, 0, stream>>>(W1, W1tb, F, H);
    trcvt<<<(H * CL + 255) / 256, 256, 0, stream>>>(W2, W2tb, H, CL);

    // gemm1: Y1t[h][m] = sum_k W1t[h][k] * x[m][k]   (M=256, N=8192, K=512)
    gemm_bt<64, 128, 32, 64, 0><<<dim3(N / 128, H / 64, 1), 256, 0, stream>>>(
        W1tb, F, xb, F, Y1tb, N, nullptr, H, N, F);

    // gemm2 (split-K=8): Hp[z][m][h] = sum_{k in eighth z} adj[m][k] * Y1t[h][k]
    gemm_adj<256, 2, 4><<<dim3(1, N / 128, 8), 512, 0, stream>>>(
        adj, Y1tb, Hp, N, N, N / 8);

    // Hb = bf16(relu(Hp0+..+Hp7 + b1))
    reduce_add<8, true><<<(N * H / 4 + 255) / 256, 256, 0, stream>>>(
        Hp, b1, Hb, N * H, H - 1);

    // gemm3: Y2t[c][m] = sum_k W2t[c][k] * H[m][k]   (M=64, N=8192, K=256)
    gemm_bt<64, 64, 32, 32, 0><<<dim3(N / 64, 1, 1), 256, 0, stream>>>(
        W2tb, H, Hb, H, Y2tb, N, nullptr, CL, N, H);

    // gemm4 (split-K=8): Zp[z][m][c] = sum_{k in eighth z} adj[m][k] * Y2t[c][k]
    gemm_adj<64, 4, 2><<<dim3(1, N / 128, 8), 512, 0, stream>>>(
        adj, Y2tb, Zp, N, N, N / 8);

    // Zb = bf16(Zp0+..+Zp7 + b2)
    reduce_add<8, false><<<(N * CL / 4 + 255) / 256, 256, 0, stream>>>(
        Zp, b2, Zb, N * CL, CL - 1);

    // gemm5: out[i][j] = sigmoid(sum_k Zb[i][k] * Zb[j][k])  (M=N=8192, K=64)
    gemm_bt<128, 128, 64, 64, 4><<<dim3(N / 128, N / 128, 1), 256, 0, stream>>>(
        Zb, CL, Zb, CL, out, N, nullptr, N, N, CL);
}

// Round 8
// 261.937 us; speedup vs baseline: 1.2506x; 1.2506x over previous
//
#include <hip/hip_runtime.h>
#include <cstdint>
#include <cstddef>

// GCN link prediction forward:
//   Y1 = x@W1; H = relu(adj@Y1 + b1); Y2 = H@W2; Z = adj@Y2 + b2; out = sigmoid(Z@Z^T)
// Architecture (measured-best across R1-R7): convert adj f32->bf16 ONCE with the
// roofline streamer (61us), then run every GEMM as bf16 MFMA gemm_bt (m97-style
// 2-barrier gload_lds loop) on L3-resident adjb. Fused-f32 variants measured
// 162-235us (latency-bound) vs cvt-once 61us — do not re-fuse.
// d_out carve (dead until gemm5 overwrites all 256 MiB at the end):
//   [0,128M)    adjb bf16 [8192][8192]
//   [128M,160M) Hp: f32 partials of gemm2   [4][8192][256]
//   [160M,176M) Zp: f32 partials of gemm4   [8][8192][64]

typedef unsigned short u16;
typedef __attribute__((ext_vector_type(8))) short short8;   // 8 bf16 (MFMA A/B frag)
typedef __attribute__((ext_vector_type(4))) float f32x4;    // MFMA C/D frag
typedef __attribute__((ext_vector_type(8))) unsigned short ushort8;
typedef __attribute__((ext_vector_type(4))) unsigned short u16x4;

__device__ __forceinline__ u16 f2bf(float v) {
    union { float f; unsigned int u; } c; c.f = v;
    unsigned int r = c.u + 0x7FFFu + ((c.u >> 16) & 1u);   // RNE
    return (u16)(r >> 16);
}

__device__ __forceinline__ void gload16(const void* g, void* l) {
    auto gp = (const __attribute__((address_space(1))) void*)(
        reinterpret_cast<uintptr_t>(g));
    auto lp = (__attribute__((address_space(3))) void*)(
        reinterpret_cast<uintptr_t>(l));
    __builtin_amdgcn_global_load_lds(gp, lp, 16, 0, 0);
}

// ---------------------------------------------------------------------------
// Templated bf16 BT-GEMM (both operands bf16). BK=64, MFMA 16x16x32.
// EPI: 0 = store bf16 ; 3 = f32 partial at blockIdx.z*M*ldc ; 4 = sigmoid f32
// ---------------------------------------------------------------------------
template <int BM, int BN, int WM, int WN, int EPI>
__launch_bounds__((BM / WM) * (BN / WN) * 64, 2)
__global__ void gemm_bt(const u16* __restrict__ A, int lda,
                        const u16* __restrict__ B, int ldb,
                        void* __restrict__ C, int ldc,
                        const float* __restrict__ bias,
                        int M, int N, int kLen) {
    constexpr int BK = 64;
    constexpr int NWCOL = BN / WN;
    constexpr int NWAVES = (BM / WM) * (BN / WN);
    constexpr int THREADS = NWAVES * 64;
    constexpr int MI = WM / 16, NI = WN / 16;
    constexpr int A_LOADS = (BM * BK * 2) / (THREADS * 16);
    constexpr int B_LOADS = (BN * BK * 2) / (THREADS * 16);

    __shared__ u16 Al[2][BM * BK];
    __shared__ u16 Bl[2][BN * BK];

    const int tid = threadIdx.x;
    const int m0 = blockIdx.y * BM;
    const int n0 = blockIdx.x * BN;
    const int kbase = blockIdx.z * kLen;

    const int l = tid & 63;
    const int w = tid >> 6;
    const int wr = w / NWCOL, wc = w % NWCOL;
    const int lr = l & 15, lk = l >> 4;

    const size_t ldab = (size_t)lda * 2, ldbb = (size_t)ldb * 2;
    const char* Abase = (const char*)(A + (size_t)m0 * lda + kbase);
    const char* Bbase = (const char*)(B + (size_t)n0 * ldb + kbase);

    auto stage = [&](int buf, int kt) {
        const char* a = Abase + (size_t)kt * (BK * 2);
        const char* b = Bbase + (size_t)kt * (BK * 2);
#pragma unroll
        for (int i = 0; i < A_LOADS; i++) {
            int off = (tid + i * THREADS) * 16;
            gload16(a + (size_t)(off >> 7) * ldab + (off & 127),
                    (char*)&Al[buf][0] + off);
        }
#pragma unroll
        for (int i = 0; i < B_LOADS; i++) {
            int off = (tid + i * THREADS) * 16;
            gload16(b + (size_t)(off >> 7) * ldbb + (off & 127),
                    (char*)&Bl[buf][0] + off);
        }
    };

    f32x4 acc[MI][NI] = {};

    const int ksteps = kLen / BK;
    stage(0, 0);
    for (int kt = 0; kt < ksteps; ++kt) {
        const int cur = kt & 1;
        __syncthreads();
        if (kt + 1 < ksteps) stage(cur ^ 1, kt + 1);
#pragma unroll
        for (int ks = 0; ks < 2; ++ks) {
            short8 af[MI];
            short8 bf[NI];
#pragma unroll
            for (int mi = 0; mi < MI; ++mi)
                af[mi] = *(const short8*)&Al[cur][(wr * WM + mi * 16 + lr) * BK + ks * 32 + lk * 8];
#pragma unroll
            for (int ni = 0; ni < NI; ++ni)
                bf[ni] = *(const short8*)&Bl[cur][(wc * WN + ni * 16 + lr) * BK + ks * 32 + lk * 8];
#pragma unroll
            for (int mi = 0; mi < MI; ++mi)
#pragma unroll
                for (int ni = 0; ni < NI; ++ni)
                    acc[mi][ni] = __builtin_amdgcn_mfma_f32_16x16x32_bf16(
                        af[mi], bf[ni], acc[mi][ni], 0, 0, 0);
        }
    }

    // epilogue: C/D frag mapping col=lane&15, row=(lane>>4)*4+r  [m89-verified]
#pragma unroll
    for (int mi = 0; mi < MI; ++mi) {
#pragma unroll
        for (int ni = 0; ni < NI; ++ni) {
            const int row = m0 + wr * WM + mi * 16 + lk * 4;
            const int col = n0 + wc * WN + ni * 16 + lr;
            f32x4 v = acc[mi][ni];
            if constexpr (EPI == 0) {
                u16* Cp = (u16*)C;
#pragma unroll
                for (int r = 0; r < 4; r++)
                    Cp[(size_t)(row + r) * ldc + col] = f2bf(v[r]);
            } else if constexpr (EPI == 3) {
                float* Cp = (float*)C + (size_t)blockIdx.z * M * ldc;
#pragma unroll
                for (int r = 0; r < 4; r++)
                    Cp[(size_t)(row + r) * ldc + col] = v[r];
            } else if constexpr (EPI == 4) {
                float* Cp = (float*)C;
#pragma unroll
                for (int r = 0; r < 4; r++) {
                    float s = 1.0f / (1.0f + __expf(-v[r]));
                    Cp[(size_t)(row + r) * ldc + col] = s;
                }
            }
        }
    }
}

// ---------------------------------------------------------------------------
// f32 -> bf16 conversion, 8 elements/thread/iter (32B read, 16B write)
// ---------------------------------------------------------------------------
__global__ void cvt8(const float* __restrict__ in, u16* __restrict__ out, int n8) {
    int stride = gridDim.x * blockDim.x;
    for (int i = blockIdx.x * blockDim.x + threadIdx.x; i < n8; i += stride) {
        f32x4 a = ((const f32x4*)in)[2 * (size_t)i];
        f32x4 b = ((const f32x4*)in)[2 * (size_t)i + 1];
        ushort8 o;
        o[0] = f2bf(a[0]); o[1] = f2bf(a[1]); o[2] = f2bf(a[2]); o[3] = f2bf(a[3]);
        o[4] = f2bf(b[0]); o[5] = f2bf(b[1]); o[6] = f2bf(b[2]); o[7] = f2bf(b[3]);
        ((ushort8*)out)[i] = o;
    }
}

__global__ void trcvt(const float* __restrict__ in, u16* __restrict__ out, int R, int C) {
    int i = blockIdx.x * blockDim.x + threadIdx.x;
    if (i < R * C) {
        int r = i / C, c = i - r * C;
        out[(size_t)c * R + r] = f2bf(in[i]);
    }
}

// split-K reduce: out[i] = bf16( [relu]( sum_z p[z][i] + bias[i & colmask] ) )
template <int PARTS, bool RELU>
__global__ void reduce_add(const float* __restrict__ p, const float* __restrict__ bias,
                           u16* __restrict__ out, int n, int colmask) {
    int i = (blockIdx.x * blockDim.x + threadIdx.x) * 4;
    if (i >= n) return;
    f32x4 acc = *(const f32x4*)(p + i);
#pragma unroll
    for (int z = 1; z < PARTS; z++) {
        f32x4 q = *(const f32x4*)(p + (size_t)z * n + i);
        acc[0] += q[0]; acc[1] += q[1]; acc[2] += q[2]; acc[3] += q[3];
    }
    u16x4 o;
#pragma unroll
    for (int j = 0; j < 4; j++) {
        float v = acc[j] + bias[(i + j) & colmask];
        if constexpr (RELU) v = v > 0.f ? v : 0.f;
        o[j] = f2bf(v);
    }
    *(u16x4*)(out + i) = o;
}

// ---------------------------------------------------------------------------
extern "C" void kernel_launch(void* const* d_in, const int* in_sizes, int n_in,
                              void* d_out, int out_size, void* d_ws, size_t ws_size,
                              hipStream_t stream) {
    constexpr int N = 8192, F = 512, H = 256, CL = 64;

    const float* x   = (const float*)d_in[0];
    const float* adj = (const float*)d_in[1];
    const float* W1  = (const float*)d_in[2];
    const float* b1  = (const float*)d_in[3];
    const float* W2  = (const float*)d_in[4];
    const float* b2  = (const float*)d_in[5];
    float* out = (float*)d_out;

    // d_out carve (all dead before gemm5 overwrites the full 256 MiB)
    u16*   adjb = (u16*)d_out;                                        // 128 MiB
    float* Hp   = (float*)((char*)d_out + (size_t)128 * 1024 * 1024); // 32 MiB: [4][8192][256]
    float* Zp   = (float*)((char*)d_out + (size_t)160 * 1024 * 1024); // 16 MiB: [8][8192][64]

    // workspace carve-up (~18.3 MB total)
    u16* xb   = (u16*)d_ws;                       // [8192][512]
    u16* W1tb = xb   + (size_t)N * F;             // [256][512]
    u16* Y1tb = W1tb + (size_t)H * F;             // [256][8192]
    u16* Hb   = Y1tb + (size_t)H * N;             // [8192][256]
    u16* W2tb = Hb   + (size_t)N * H;             // [64][256]
    u16* Y2tb = W2tb + (size_t)CL * H;            // [64][8192]
    u16* Zb   = Y2tb + (size_t)CL * N;            // [8192][64]

    // conversions (cvt8 on adj is the roofline streamer: 402 MB @ ~6.3 TB/s)
    cvt8<<<2048, 256, 0, stream>>>(adj, adjb, N * N / 8);
    cvt8<<<256, 256, 0, stream>>>(x, xb, N * F / 8);
    trcvt<<<(F * H + 255) / 256, 256, 0, stream>>>(W1, W1tb, F, H);
    trcvt<<<(H * CL + 255) / 256, 256, 0, stream>>>(W2, W2tb, H, CL);

    // gemm1: Y1t[h][m] = sum_k W1t[h][k] * x[m][k]   (M=256, N=8192, K=512)
    gemm_bt<64, 128, 32, 64, 0><<<dim3(N / 128, H / 64, 1), 256, 0, stream>>>(
        W1tb, F, xb, F, Y1tb, N, nullptr, H, N, F);

    // gemm2 (split-K=4 -> 512 blocks = 2 blocks/CU):
    //   Hp[z][m][h] = sum_{k in quarter z} adjb[m][k] * Y1t[h][k]
    gemm_bt<128, 128, 64, 64, 3><<<dim3(H / 128, N / 128, 4), 256, 0, stream>>>(
        adjb, N, Y1tb, N, Hp, H, nullptr, N, H, N / 4);

    // Hb = bf16(relu(Hp0+..+Hp3 + b1))
    reduce_add<4, true><<<(N * H / 4 + 255) / 256, 256, 0, stream>>>(
        Hp, b1, Hb, N * H, H - 1);

    // gemm3: Y2t[c][m] = sum_k W2t[c][k] * H[m][k]   (M=64, N=8192, K=256)
    gemm_bt<64, 64, 32, 32, 0><<<dim3(N / 64, 1, 1), 256, 0, stream>>>(
        W2tb, H, Hb, H, Y2tb, N, nullptr, CL, N, H);

    // gemm4 (split-K=8 -> 512 blocks): Zp[z][m][c] = sum_{k in eighth z} adjb[m][k] * Y2t[c][k]
    gemm_bt<128, 64, 64, 32, 3><<<dim3(1, N / 128, 8), 256, 0, stream>>>(
        adjb, N, Y2tb, N, Zp, CL, nullptr, N, CL, N / 8);

    // Zb = bf16(Zp0+..+Zp7 + b2)
    reduce_add<8, false><<<(N * CL / 4 + 255) / 256, 256, 0, stream>>>(
        Zp, b2, Zb, N * CL, CL - 1);

    // gemm5: out[i][j] = sigmoid(sum_k Zb[i][k] * Zb[j][k])  (M=N=8192, K=64)
    gemm_bt<128, 128, 64, 64, 4><<<dim3(N / 128, N / 128, 1), 256, 0, stream>>>(
        Zb, CL, Zb, CL, out, N, nullptr, N, N, CL);
}